// Round 1
// baseline (6088.061 us; speedup 1.0000x reference)
//
#include <hip/hip_runtime.h>

// DecoderRNN: 3-layer GRU, B=32768, H=100, 21 steps, VOCAB=20.
// Design: 1 wave (64 thr) per 16 batch rows; entire recurrence in-wave,
// barrier-free. h-state bf16 in LDS [16][136]; weights pre-padded bf16 in ws.
// MFMA 16x16x32_bf16, K 100->128 pad, N 100->112 pad (7 tiles/gate).

#define B_TOTAL 32768
#define NT 7            // 112/16 n-tiles per gate

using frag  = __attribute__((ext_vector_type(8))) short;  // 8 bf16
using f32x4 = __attribute__((ext_vector_type(4))) float;

__device__ __forceinline__ unsigned short f2b(float f) {
    union { float f; unsigned u; } v; v.f = f;
    unsigned r = v.u + 0x7FFF + ((v.u >> 16) & 1);        // RNE
    return (unsigned short)(r >> 16);
}
__device__ __forceinline__ float b2f(unsigned short b) {
    union { unsigned u; float f; } v; v.u = ((unsigned)b) << 16; return v.f;
}
__device__ __forceinline__ float sigm(float x) { return 1.f / (1.f + __expf(-x)); }
__device__ __forceinline__ float tanh_fast(float x) { return 2.f / (1.f + __expf(-2.f * x)) - 1.f; }

__device__ __forceinline__ f32x4 mfma(frag a, frag b, f32x4 c) {
    return __builtin_amdgcn_mfma_f32_16x16x32_bf16(a, b, c, 0, 0, 0);
}

// ---------------- weight prep: f32 -> bf16, padded ----------------
// ws layout (elements of u16):
//   [0)        w_proj  [112][128]   (src [100][128])          14336
//   [14336)    ih0,hh0,ih1,hh1,ih2,hh2  each [336][128]       6*43008
//              (src [300][100]; n = g*112+nn, valid nn<100,k<100)
//   [272384)   w_out  [32][128]     (src [20][100])           4096
#define WP_TOTAL 276480

__global__ void prep_kernel(const float* __restrict__ w_proj,
                            const float* __restrict__ wih0, const float* __restrict__ whh0,
                            const float* __restrict__ wih1, const float* __restrict__ whh1,
                            const float* __restrict__ wih2, const float* __restrict__ whh2,
                            const float* __restrict__ w_out,
                            unsigned short* __restrict__ dst) {
    int idx = blockIdx.x * 256 + threadIdx.x;
    if (idx >= WP_TOTAL) return;
    float v = 0.f;
    if (idx < 14336) {
        int n = idx >> 7, k = idx & 127;
        if (n < 100) v = w_proj[n * 128 + k];
    } else if (idx < 272384) {
        int r = idx - 14336;
        int mi = r / 43008;
        int e  = r - mi * 43008;
        int n = e >> 7, k = e & 127;          // n in [0,336)
        int g = n / 112, nn = n - g * 112;
        if (nn < 100 && k < 100) {
            const float* src = (mi == 0) ? wih0 : (mi == 1) ? whh0 :
                               (mi == 2) ? wih1 : (mi == 3) ? whh1 :
                               (mi == 4) ? wih2 : whh2;
            v = src[(g * 100 + nn) * 100 + k];
        }
    } else {
        int e = idx - 272384;
        int n = e >> 7, k = e & 127;
        if (n < 20 && k < 100) v = w_out[n * 100 + k];
    }
    dst[idx] = f2b(v);
}

// ---------------- GRU phase helpers ----------------
// h tile: [16][136] bf16 in LDS. A-frag: lane l reads h[l&15][kb*32+(l>>4)*8 .. +8]
__device__ __forceinline__ void load_afrags(const unsigned short (*h)[136], int c16, int g4, frag* A) {
#pragma unroll
    for (int kb = 0; kb < 4; ++kb)
        A[kb] = *(const frag*)&h[c16][kb * 32 + g4 * 8];
}

// gh = h @ whh^T + bhh (acc-init), fused GRU elementwise, h updated in place.
__device__ __forceinline__ void gru_phase(unsigned short (*h)[136],
                                          const unsigned short* __restrict__ whh,
                                          const float* __restrict__ bhh,
                                          const f32x4* gr, const f32x4* gz, const f32x4* gn,
                                          int c16, int g4) {
    frag A[4];
    load_afrags(h, c16, g4, A);
#pragma unroll
    for (int t = 0; t < NT; ++t) {
        int col = t * 16 + c16;
        float br = 0.f, bz = 0.f, bn = 0.f;
        if (col < 100) { br = bhh[col]; bz = bhh[100 + col]; bn = bhh[200 + col]; }
        f32x4 ar = {br, br, br, br}, az = {bz, bz, bz, bz}, an = {bn, bn, bn, bn};
        const unsigned short* wb = whh + (size_t)(t * 16 + c16) * 128 + g4 * 8;
#pragma unroll
        for (int kb = 0; kb < 4; ++kb) ar = mfma(A[kb], *(const frag*)(wb + kb * 32), ar);
        wb += (size_t)112 * 128;
#pragma unroll
        for (int kb = 0; kb < 4; ++kb) az = mfma(A[kb], *(const frag*)(wb + kb * 32), az);
        wb += (size_t)112 * 128;
#pragma unroll
        for (int kb = 0; kb < 4; ++kb) an = mfma(A[kb], *(const frag*)(wb + kb * 32), an);
#pragma unroll
        for (int j = 0; j < 4; ++j) {
            int lr = g4 * 4 + j;
            float r  = sigm(gr[t][j] + ar[j]);
            float z  = sigm(gz[t][j] + az[j]);
            float nn = tanh_fast(gn[t][j] + r * an[j]);
            float ho = b2f(h[lr][col]);
            float hn = (1.f - z) * nn + z * ho;
            if (col < 100) h[lr][col] = f2b(hn);
        }
    }
}

// gx = h_src @ wih^T + bih  -> register arrays
__device__ __forceinline__ void wih_phase(const unsigned short (*hsrc)[136],
                                          const unsigned short* __restrict__ wih,
                                          const float* __restrict__ bih,
                                          f32x4* gr, f32x4* gz, f32x4* gn,
                                          int c16, int g4) {
    frag A[4];
    load_afrags(hsrc, c16, g4, A);
#pragma unroll
    for (int t = 0; t < NT; ++t) {
        int col = t * 16 + c16;
        float br = 0.f, bz = 0.f, bn = 0.f;
        if (col < 100) { br = bih[col]; bz = bih[100 + col]; bn = bih[200 + col]; }
        f32x4 ar = {br, br, br, br}, az = {bz, bz, bz, bz}, an = {bn, bn, bn, bn};
        const unsigned short* wb = wih + (size_t)(t * 16 + c16) * 128 + g4 * 8;
#pragma unroll
        for (int kb = 0; kb < 4; ++kb) ar = mfma(A[kb], *(const frag*)(wb + kb * 32), ar);
        wb += (size_t)112 * 128;
#pragma unroll
        for (int kb = 0; kb < 4; ++kb) az = mfma(A[kb], *(const frag*)(wb + kb * 32), az);
        wb += (size_t)112 * 128;
#pragma unroll
        for (int kb = 0; kb < 4; ++kb) an = mfma(A[kb], *(const frag*)(wb + kb * 32), an);
        gr[t] = ar; gz[t] = az; gn[t] = an;
    }
}

// ---------------- main kernel: one wave = 16 batch rows ----------------
__global__ __launch_bounds__(64, 2) void rnn_kernel(
    const float* __restrict__ enc,
    const float* __restrict__ b_proj,
    const float* __restrict__ bih0, const float* __restrict__ bhh0,
    const float* __restrict__ bih1, const float* __restrict__ bhh1,
    const float* __restrict__ bih2, const float* __restrict__ bhh2,
    const float* __restrict__ b_out,
    const unsigned short* __restrict__ wp,
    float* __restrict__ out) {
    __shared__ unsigned short hb[3][16][136];
    const int lane = threadIdx.x;
    const int c16 = lane & 15;
    const int g4  = lane >> 4;
    const int rbase = blockIdx.x * 16;

    const unsigned short* wp_proj = wp;
    const unsigned short* wp_ih0  = wp + 14336;
    const unsigned short* wp_hh0  = wp + 14336 + 1 * 43008;
    const unsigned short* wp_ih1  = wp + 14336 + 2 * 43008;
    const unsigned short* wp_hh1  = wp + 14336 + 3 * 43008;
    const unsigned short* wp_ih2  = wp + 14336 + 4 * 43008;
    const unsigned short* wp_hh2  = wp + 14336 + 5 * 43008;
    const unsigned short* wp_out  = wp + 272384;

    // zero all LDS (h pad must be 0; single wave -> no barrier needed anywhere)
    {
        unsigned short* p = &hb[0][0][0];
        for (int i = lane; i < 3 * 16 * 136; i += 64) p[i] = 0;
    }

    // ---- prologue: x0 = enc @ w_proj^T + b_proj  (K=128 exact) ----
    frag Ae[4];
    {
        const float* erow = enc + (size_t)(rbase + c16) * 128;
#pragma unroll
        for (int kb = 0; kb < 4; ++kb) {
            const float* p = erow + kb * 32 + g4 * 8;
            frag a;
#pragma unroll
            for (int j = 0; j < 8; ++j) a[j] = (short)f2b(p[j]);
            Ae[kb] = a;
        }
    }
#pragma unroll
    for (int t = 0; t < NT; ++t) {
        int col = t * 16 + c16;
        float bv = (col < 100) ? b_proj[col] : 0.f;
        f32x4 acc = {bv, bv, bv, bv};
#pragma unroll
        for (int kb = 0; kb < 4; ++kb) {
            frag b = *(const frag*)(wp_proj + (size_t)(t * 16 + c16) * 128 + kb * 32 + g4 * 8);
            acc = mfma(Ae[kb], b, acc);
        }
        if (col < 100) {
#pragma unroll
            for (int j = 0; j < 4; ++j) hb[2][g4 * 4 + j][col] = f2b(acc[j]);  // tempX in h2
        }
    }

    // ---- gx0 = x0 @ wih0^T + bih0 -> persistent registers ----
    f32x4 gx0r[NT], gx0z[NT], gx0n[NT];
    wih_phase(hb[2], wp_ih0, bih0, gx0r, gx0z, gx0n, c16, g4);

    // reset h2 (tempX) to zero
    {
        unsigned short* p = &hb[2][0][0];
        for (int i = lane; i < 16 * 136; i += 64) p[i] = 0;
    }

    // ---- time loop ----
    f32x4 g1r[NT], g1z[NT], g1n[NT];
#pragma unroll 1
    for (int ts = 0; ts < 21; ++ts) {
        gru_phase(hb[0], wp_hh0, bhh0, gx0r, gx0z, gx0n, c16, g4);
        wih_phase(hb[0], wp_ih1, bih1, g1r, g1z, g1n, c16, g4);
        gru_phase(hb[1], wp_hh1, bhh1, g1r, g1z, g1n, c16, g4);
        wih_phase(hb[1], wp_ih2, bih2, g1r, g1z, g1n, c16, g4);
        gru_phase(hb[2], wp_hh2, bhh2, g1r, g1z, g1n, c16, g4);

        // logits = h2 @ w_out^T + b_out -> d_out[row][ts][0..20)
        frag A[4];
        load_afrags(hb[2], c16, g4, A);
#pragma unroll
        for (int nt = 0; nt < 2; ++nt) {
            int col = nt * 16 + c16;
            float bv = (col < 20) ? b_out[col] : 0.f;
            f32x4 acc = {bv, bv, bv, bv};
#pragma unroll
            for (int kb = 0; kb < 4; ++kb) {
                frag b = *(const frag*)(wp_out + (size_t)(nt * 16 + c16) * 128 + kb * 32 + g4 * 8);
                acc = mfma(A[kb], b, acc);
            }
            if (col < 20) {
#pragma unroll
                for (int j = 0; j < 4; ++j) {
                    size_t row = (size_t)(rbase + g4 * 4 + j);
                    out[(row * 21 + ts) * 20 + col] = acc[j];
                }
            }
        }
    }
}

extern "C" void kernel_launch(void* const* d_in, const int* in_sizes, int n_in,
                              void* d_out, int out_size, void* d_ws, size_t ws_size,
                              hipStream_t stream) {
    const float* enc    = (const float*)d_in[0];
    const float* w_proj = (const float*)d_in[1];
    const float* b_proj = (const float*)d_in[2];
    const float* wih0   = (const float*)d_in[3];
    const float* whh0   = (const float*)d_in[4];
    const float* bih0   = (const float*)d_in[5];
    const float* bhh0   = (const float*)d_in[6];
    const float* wih1   = (const float*)d_in[7];
    const float* whh1   = (const float*)d_in[8];
    const float* bih1   = (const float*)d_in[9];
    const float* bhh1   = (const float*)d_in[10];
    const float* wih2   = (const float*)d_in[11];
    const float* whh2   = (const float*)d_in[12];
    const float* bih2   = (const float*)d_in[13];
    const float* bhh2   = (const float*)d_in[14];
    const float* w_out  = (const float*)d_in[15];
    const float* b_out  = (const float*)d_in[16];
    unsigned short* wp  = (unsigned short*)d_ws;   // 552,960 B used
    float* out          = (float*)d_out;

    prep_kernel<<<(WP_TOTAL + 255) / 256, 256, 0, stream>>>(
        w_proj, wih0, whh0, wih1, whh1, wih2, whh2, w_out, wp);
    rnn_kernel<<<B_TOTAL / 16, 64, 0, stream>>>(
        enc, b_proj, bih0, bhh0, bih1, bhh1, bih2, bhh2, b_out, wp, out);
}

// Round 3
// 809.823 us; speedup vs baseline: 7.5178x; 7.5178x over previous
//
#include <hip/hip_runtime.h>

// DecoderRNN v3: 3-layer GRU, B=32768, H=100, 21 steps, VOCAB=20.
// Block = 8 waves x 128 batch rows (1 block/CU). Waves 0..6 own 16-neuron
// output tiles; wave 7 computes logits (1 step behind) during gru0.
// All three layers use ONE uniform phase: gx = S @ wih^T, gh = D @ whh^T,
// biases folded into weight col k=100 against h[.][100]==1.0.
// Weights bf16, streamed per phase from L2 (wp = 553 KB, L2-resident).
// K=100+bias split: 3x k32 MFMA + 1x k32 "tail" MFMA where only g4==0 lanes
// carry data (k 96..103) and all other lanes read guaranteed zeros.
// h/x0 LDS buffers: [128 rows][128 u16], 16B-chunk XOR swizzle (chunk ^= row&7).

#define NTHR 512
#define NBLK 256
#define ROWS_PB 128

// wp (u16) offsets
#define OFF_PROJ 0                 // [112][128]
#define OFF_IH0  14336             // each [336][128]: row g*112+nn, col 100 = bias
#define OFF_HH0  57344
#define OFF_IH1  100352
#define OFF_HH1  143360
#define OFF_IH2  186368
#define OFF_HH2  229376
#define OFF_OUT  272384            // [32][128], col 100 = b_out
#define Z16_OFF  275456            // 16 B of zeros (wout pad rows)
#define WP_TOTAL 276480

// LDS (u16): 4 buffers [128][128] swizzled + 8-u16 zero pad
#define X0_OFF   0
#define H0_OFF   16384
#define H1_OFF   32768
#define H2_OFF   49152
#define ZPAD_OFF 65536
#define SMEM_U16 65544
#define SMEM_BYTES (SMEM_U16 * 2)  // 131088

using frag8 = __attribute__((ext_vector_type(8))) short;
using frag4 = __attribute__((ext_vector_type(4))) short;
using f32x4 = __attribute__((ext_vector_type(4))) float;

struct G3 { frag8 a, b, c; };

__device__ __forceinline__ unsigned short f2b(float f) {
    union { float f; unsigned u; } v; v.f = f;
    unsigned r = v.u + 0x7FFF + ((v.u >> 16) & 1);   // RNE
    return (unsigned short)(r >> 16);
}
__device__ __forceinline__ float b2f(unsigned short b) {
    union { unsigned u; float f; } v; v.u = ((unsigned)b) << 16; return v.f;
}
__device__ __forceinline__ float sigm(float x) { return 1.f / (1.f + __expf(-x)); }
__device__ __forceinline__ float tanh_fast(float x) { return 2.f / (1.f + __expf(-2.f * x)) - 1.f; }

__device__ __forceinline__ f32x4 mfma32(frag8 a, frag8 b, f32x4 c) {
    return __builtin_amdgcn_mfma_f32_16x16x32_bf16(a, b, c, 0, 0, 0);
}
__device__ __forceinline__ f32x4 dot3(const G3& w, const G3& s, f32x4 acc) {
    acc = mfma32(w.a, s.a, acc);
    acc = mfma32(w.b, s.b, acc);
    return mfma32(w.c, s.c, acc);
}

// ---------------- weight prep: f32 -> bf16, padded, bias in col 100 ----------------
__global__ void prep_kernel(const float* __restrict__ w_proj,
    const float* __restrict__ wih0, const float* __restrict__ bih0,
    const float* __restrict__ whh0, const float* __restrict__ bhh0,
    const float* __restrict__ wih1, const float* __restrict__ bih1,
    const float* __restrict__ whh1, const float* __restrict__ bhh1,
    const float* __restrict__ wih2, const float* __restrict__ bih2,
    const float* __restrict__ whh2, const float* __restrict__ bhh2,
    const float* __restrict__ w_out, const float* __restrict__ b_out,
    unsigned short* __restrict__ dst)
{
    int idx = blockIdx.x * 256 + threadIdx.x;
    if (idx >= WP_TOTAL) return;
    float v = 0.f;
    if (idx < OFF_IH0) {
        int n = idx >> 7, k = idx & 127;
        if (n < 100) v = w_proj[n * 128 + k];
    } else if (idx < OFF_OUT) {
        int r = idx - OFF_IH0;
        int mi = r / 43008;
        int e  = r - mi * 43008;
        int n = e >> 7, k = e & 127;
        int g = n / 112, nn = n - g * 112;
        if (nn < 100) {
            const float* W; const float* Bv;
            switch (mi) {
                case 0: W = wih0; Bv = bih0; break;
                case 1: W = whh0; Bv = bhh0; break;
                case 2: W = wih1; Bv = bih1; break;
                case 3: W = whh1; Bv = bhh1; break;
                case 4: W = wih2; Bv = bih2; break;
                default: W = whh2; Bv = bhh2; break;
            }
            if (k < 100) v = W[(g * 100 + nn) * 100 + k];
            else if (k == 100) v = Bv[g * 100 + nn];
        }
    } else {
        int e = idx - OFF_OUT;
        int n = e >> 7, k = e & 127;
        if (n < 20) {
            if (k < 100) v = w_out[n * 100 + k];
            else if (k == 100) v = b_out[n];
        }
    }
    dst[idx] = f2b(v);
}

// ---------------- LDS helpers (swizzled) ----------------
// logical u16 col cu of buffer-row r stored at chunk (cu>>3) ^ (r&7)
__device__ __forceinline__ int hsw(int buf, int grp, int r, int cu) {
    return buf + (grp * 16 + r) * 128 + ((((cu >> 3) ^ (r & 7)) << 3) | (cu & 7));
}
__device__ __forceinline__ G3 ldS3(const unsigned short* sm, int buf, int grp, int c16, int g4) {
    const unsigned short* p = sm + buf + (grp * 16 + c16) * 128;
    int x = c16 & 7;
    G3 s;
    s.a = *(const frag8*)(p + ((g4 ^ x) << 3));
    s.b = *(const frag8*)(p + (((4 + g4) ^ x) << 3));
    s.c = *(const frag8*)(p + (((8 + g4) ^ x) << 3));
    return s;
}
__device__ __forceinline__ frag8 ldTail(const unsigned short* sm, int buf, int grp, int c16, int g4) {
    int off = (g4 == 0) ? (buf + (grp * 16 + c16) * 128 + ((12 ^ (c16 & 7)) << 3)) : ZPAD_OFF;
    return *(const frag8*)(sm + off);
}

// ---------------- weight loaders (global, per-phase stream) ----------------
__device__ __forceinline__ G3 ldW(const unsigned short* __restrict__ mat, int g, int ro, int g4) {
    const unsigned short* p = mat + (size_t)(g * 112 + ro) * 128 + g4 * 8;
    G3 w; w.a = *(const frag8*)p; w.b = *(const frag8*)(p + 32); w.c = *(const frag8*)(p + 64);
    return w;
}
__device__ __forceinline__ frag8 ldWT(const unsigned short* __restrict__ mat,
                                      const unsigned short* __restrict__ z16, int g, int ro, int g4) {
    const unsigned short* p = (g4 == 0) ? (mat + (size_t)(g * 112 + ro) * 128 + 96) : z16;
    return *(const frag8*)p;
}

__device__ __forceinline__ void logits_one(const unsigned short* sm,
        const G3& O0, const G3& O1, frag8 T0, frag8 T1,
        int grp, int lt, float* __restrict__ out, int rbase, int c16, int g4) {
    G3 L = ldS3(sm, H2_OFF, grp, c16, g4);
    frag8 LT = ldTail(sm, H2_OFF, grp, c16, g4);
    f32x4 a0 = {0.f, 0.f, 0.f, 0.f}, a1 = a0;
    a0 = dot3(O0, L, a0); a0 = mfma32(T0, LT, a0);
    a1 = dot3(O1, L, a1); a1 = mfma32(T1, LT, a1);
    float* po = out + (size_t)(rbase + grp * 16 + c16) * 420 + lt * 20;
    *(f32x4*)(po + g4 * 4) = a0;           // vocab 4*g4 .. +4
    if (g4 == 0) *(f32x4*)(po + 16) = a1;  // vocab 16..19
}

// ---------------- one GRU layer phase (uniform for layers 0/1/2) ----------------
__device__ __forceinline__ void gru_phase(
    unsigned short* sm, int HS, int HD,
    const unsigned short* __restrict__ wih, const unsigned short* __restrict__ whh,
    const unsigned short* __restrict__ z16,
    const unsigned short* __restrict__ wout,   // non-null => wave 7 does logits(lt)
    int lt, float* __restrict__ out, int rbase,
    bool owner, bool vald, int c16, int g4, int ro, int nbase)
{
    G3 Wir, Wiz, Win, Whr, Whz, Whn;
    frag8 Tir, Tiz, Tin, Thr, Thz, Thn;
    G3 Dc; frag8 TDc;
    const bool do_log = (!owner) && (wout != nullptr) && (lt >= 0);
    if (owner) {
        Wir = ldW(wih, 0, ro, g4); Wiz = ldW(wih, 1, ro, g4); Win = ldW(wih, 2, ro, g4);
        Whr = ldW(whh, 0, ro, g4); Whz = ldW(whh, 1, ro, g4); Whn = ldW(whh, 2, ro, g4);
        Tir = ldWT(wih, z16, 0, ro, g4); Tiz = ldWT(wih, z16, 1, ro, g4); Tin = ldWT(wih, z16, 2, ro, g4);
        Thr = ldWT(whh, z16, 0, ro, g4); Thz = ldWT(whh, z16, 1, ro, g4); Thn = ldWT(whh, z16, 2, ro, g4);
        Dc = ldS3(sm, HD, 0, c16, g4); TDc = ldTail(sm, HD, 0, c16, g4);
    } else if (do_log) {
        const unsigned short* p0 = wout + (size_t)c16 * 128 + g4 * 8;
        Wir.a = *(const frag8*)p0; Wir.b = *(const frag8*)(p0 + 32); Wir.c = *(const frag8*)(p0 + 64);
        const unsigned short* p1 = wout + (size_t)(16 + c16) * 128 + g4 * 8;
        Wiz.a = *(const frag8*)p1; Wiz.b = *(const frag8*)(p1 + 32); Wiz.c = *(const frag8*)(p1 + 64);
        Tir = *(const frag8*)((g4 == 0) ? (wout + (size_t)c16 * 128 + 96) : z16);
        Tiz = *(const frag8*)((g4 == 0) ? (wout + (size_t)(16 + c16) * 128 + 96) : z16);
    }
#pragma unroll 1
    for (int grp = 0; grp < 8; ++grp) {
        __syncthreads();
        if (owner) {
            G3 S = ldS3(sm, HS, grp, c16, g4);
            frag8 TS = ldTail(sm, HS, grp, c16, g4);
            f32x4 ar = {0.f, 0.f, 0.f, 0.f}, az = ar, anx = ar, anh = ar;
            ar = dot3(Wir, S, ar); az = dot3(Wiz, S, az); anx = dot3(Win, S, anx);
            ar = mfma32(Tir, TS, ar); az = mfma32(Tiz, TS, az); anx = mfma32(Tin, TS, anx);
            ar = dot3(Whr, Dc, ar); az = dot3(Whz, Dc, az); anh = dot3(Whn, Dc, anh);
            ar = mfma32(Thr, TDc, ar); az = mfma32(Thz, TDc, az); anh = mfma32(Thn, TDc, anh);
            if (grp < 7) { Dc = ldS3(sm, HD, grp + 1, c16, g4); TDc = ldTail(sm, HD, grp + 1, c16, g4); }
            int wo = hsw(HD, grp, c16, nbase);
            frag4 hold = {0, 0, 0, 0};
            if (vald) hold = *(const frag4*)(sm + wo);
            frag4 hn;
#pragma unroll
            for (int j = 0; j < 4; ++j) {
                float r  = sigm(ar[j]);
                float z  = sigm(az[j]);
                float nn = tanh_fast(anx[j] + r * anh[j]);
                float ho = b2f((unsigned short)hold[j]);
                hn[j] = (short)f2b((1.f - z) * nn + z * ho);
            }
            if (vald) *(frag4*)(sm + wo) = hn;
        } else if (do_log) {
            logits_one(sm, Wir, Wiz, Tir, Tiz, grp, lt, out, rbase, c16, g4);
        }
    }
}

// ---------------- main kernel ----------------
__global__ __launch_bounds__(NTHR, 2) void rnn_kernel(
    const float* __restrict__ enc,
    const float* __restrict__ b_proj,
    const unsigned short* __restrict__ wp,
    float* __restrict__ out)
{
    extern __shared__ unsigned short sm[];
    const int tid  = threadIdx.x;
    const int lane = tid & 63;
    const int wid  = tid >> 6;
    const int c16  = lane & 15;
    const int g4   = lane >> 4;
    const int rbase = blockIdx.x * ROWS_PB;
    const bool owner = (wid < 7);
    const int tw    = owner ? wid : 0;
    const int ro    = tw * 16 + c16;
    const int nbase = tw * 16 + g4 * 4;
    const bool vald = owner && (nbase < 100);
    const unsigned short* z16 = wp + Z16_OFF;

    // ---- init LDS: zeros, logical col 100 = 1.0 (bias), ZPAD = 0 ----
    for (int i = tid; i < SMEM_U16; i += NTHR) {
        unsigned short v = 0;
        if (i < ZPAD_OFF) {
            int r  = (i >> 7) & 127;
            int cu = i & 127;
            int lcol = ((((cu >> 3) ^ (r & 7)) << 3) | (cu & 7));
            if (lcol == 100) v = 0x3F80;
        }
        sm[i] = v;
    }
    __syncthreads();

    // ---- prologue: x0 = enc @ w_proj^T + b_proj -> X0 buffer (K=128 exact) ----
    if (owner) {
        const unsigned short* pr = wp + OFF_PROJ + (size_t)ro * 128 + g4 * 8;
        frag8 P0 = *(const frag8*)pr,        P1 = *(const frag8*)(pr + 32);
        frag8 P2 = *(const frag8*)(pr + 64), P3 = *(const frag8*)(pr + 96);
        f32x4 bp = {0.f, 0.f, 0.f, 0.f};
        if (vald) bp = *(const f32x4*)(b_proj + nbase);
#pragma unroll 1
        for (int grp = 0; grp < 8; ++grp) {
            const float* ep = enc + (size_t)(rbase + grp * 16 + c16) * 128 + g4 * 8;
            frag8 E[4];
#pragma unroll
            for (int kb = 0; kb < 4; ++kb) {
                f32x4 u = *(const f32x4*)(ep + kb * 32);
                f32x4 v = *(const f32x4*)(ep + kb * 32 + 4);
                frag8 e;
#pragma unroll
                for (int j = 0; j < 4; ++j) { e[j] = (short)f2b(u[j]); e[4 + j] = (short)f2b(v[j]); }
                E[kb] = e;
            }
            f32x4 acc = bp;
            acc = mfma32(P0, E[0], acc); acc = mfma32(P1, E[1], acc);
            acc = mfma32(P2, E[2], acc); acc = mfma32(P3, E[3], acc);
            if (vald) {
                frag4 xv;
#pragma unroll
                for (int j = 0; j < 4; ++j) xv[j] = (short)f2b(acc[j]);
                *(frag4*)(sm + hsw(X0_OFF, grp, c16, nbase)) = xv;
            }
        }
    }
    __syncthreads();

    // ---- time loop: three uniform phases; wave 7 logits(t-1) during gru0 ----
#pragma unroll 1
    for (int t = 0; t < 21; ++t) {
        gru_phase(sm, X0_OFF, H0_OFF, wp + OFF_IH0, wp + OFF_HH0, z16,
                  wp + OFF_OUT, t - 1, out, rbase, owner, vald, c16, g4, ro, nbase);
        gru_phase(sm, H0_OFF, H1_OFF, wp + OFF_IH1, wp + OFF_HH1, z16,
                  nullptr, -1, out, rbase, owner, vald, c16, g4, ro, nbase);
        gru_phase(sm, H1_OFF, H2_OFF, wp + OFF_IH2, wp + OFF_HH2, z16,
                  nullptr, -1, out, rbase, owner, vald, c16, g4, ro, nbase);
    }

    // ---- tail: logits for t=20 (wave 7) ----
    __syncthreads();
    if (!owner) {
        const unsigned short* wout = wp + OFF_OUT;
        G3 O0, O1; frag8 T0, T1;
        const unsigned short* p0 = wout + (size_t)c16 * 128 + g4 * 8;
        O0.a = *(const frag8*)p0; O0.b = *(const frag8*)(p0 + 32); O0.c = *(const frag8*)(p0 + 64);
        const unsigned short* p1 = wout + (size_t)(16 + c16) * 128 + g4 * 8;
        O1.a = *(const frag8*)p1; O1.b = *(const frag8*)(p1 + 32); O1.c = *(const frag8*)(p1 + 64);
        T0 = *(const frag8*)((g4 == 0) ? (wout + (size_t)c16 * 128 + 96) : z16);
        T1 = *(const frag8*)((g4 == 0) ? (wout + (size_t)(16 + c16) * 128 + 96) : z16);
#pragma unroll 1
        for (int grp = 0; grp < 8; ++grp)
            logits_one(sm, O0, O1, T0, T1, grp, 20, out, rbase, c16, g4);
    }
}

extern "C" void kernel_launch(void* const* d_in, const int* in_sizes, int n_in,
                              void* d_out, int out_size, void* d_ws, size_t ws_size,
                              hipStream_t stream) {
    const float* enc    = (const float*)d_in[0];
    const float* w_proj = (const float*)d_in[1];
    const float* b_proj = (const float*)d_in[2];
    const float* wih0   = (const float*)d_in[3];
    const float* whh0   = (const float*)d_in[4];
    const float* bih0   = (const float*)d_in[5];
    const float* bhh0   = (const float*)d_in[6];
    const float* wih1   = (const float*)d_in[7];
    const float* whh1   = (const float*)d_in[8];
    const float* bih1   = (const float*)d_in[9];
    const float* bhh1   = (const float*)d_in[10];
    const float* wih2   = (const float*)d_in[11];
    const float* whh2   = (const float*)d_in[12];
    const float* bih2   = (const float*)d_in[13];
    const float* bhh2   = (const float*)d_in[14];
    const float* w_out  = (const float*)d_in[15];
    const float* b_out  = (const float*)d_in[16];
    unsigned short* wpd = (unsigned short*)d_ws;   // 552,960 B used
    float* out          = (float*)d_out;

    prep_kernel<<<(WP_TOTAL + 255) / 256, 256, 0, stream>>>(
        w_proj, wih0, bih0, whh0, bhh0, wih1, bih1, whh1, bhh1,
        wih2, bih2, whh2, bhh2, w_out, b_out, wpd);

    (void)hipFuncSetAttribute((const void*)rnn_kernel,
                              hipFuncAttributeMaxDynamicSharedMemorySize, SMEM_BYTES);
    rnn_kernel<<<NBLK, NTHR, SMEM_BYTES, stream>>>(enc, b_proj, wpd, out);
}